// Round 12
// baseline (558.969 us; speedup 1.0000x reference)
//
#include <hip/hip_runtime.h>
#include <math.h>

// Problem constants (reference: B,N,M,C = 4,4096,4096,256)
#define BB 4
#define BN 4096          // N == M == 4096
#define CC 256
constexpr float T2      = 0.04f;                     // DIST_THRESH^2
constexpr float INV_EPS = (float)(1.0 / 0.01000001); // 1/(EPSILON + 1e-8)

typedef __attribute__((ext_vector_type(8)))  short bf16x8;
typedef __attribute__((ext_vector_type(16))) float f32x16;

__device__ __forceinline__ int cell_of(float x, float y) {
  int cx = (int)(x * 5.0f); cx = cx < 0 ? 0 : (cx > 4 ? 4 : cx);
  int cy = (int)(y * 5.0f); cy = cy < 0 ? 0 : (cy > 4 ? 4 : cy);
  return cy * 5 + cx;
}

// ------------------------------------------------- fused binning (8 blk) ----
__global__ __launch_bounds__(256) void k_bin(
    const float* __restrict__ tlocs, const float* __restrict__ slocs,
    const int* __restrict__ tmask, const int* __restrict__ smask,
    int* __restrict__ Zc, int* __restrict__ qcnt,
    int* __restrict__ starts_t, int* __restrict__ starts_s,
    int* __restrict__ perm_t, int* __restrict__ perm_s,
    float4* __restrict__ t_sorted, float4* __restrict__ s_sorted) {
  const int which = blockIdx.x & 1, b = blockIdx.x >> 1;   // grid = 2*B
  const float* locs = which ? slocs : tlocs;
  const int*   mask = which ? smask : tmask;
  int* starts       = which ? starts_s : starts_t;
  int* perm         = which ? perm_s : perm_t;
  float4* pack      = which ? s_sorted : t_sorted;
  const int tid = threadIdx.x;
  if (blockIdx.x == 0) {
    Zc[tid] = 0;                                           // 256 ints = 1 KB
    if (tid == 0) qcnt[0] = 0;                             // k_out work queue
  }
  __shared__ int cnt[25];
  __shared__ int st[26];
  __shared__ int cur[25];
  if (tid < 25) cnt[tid] = 0;
  __syncthreads();
  for (int i = tid; i < BN; i += 256)
    atomicAdd(&cnt[cell_of(locs[(b * BN + i) * 2], locs[(b * BN + i) * 2 + 1])], 1);
  __syncthreads();
  if (tid == 0) {
    int acc = 0;
    for (int c = 0; c < 25; c++) { st[c] = acc; acc += cnt[c]; }
    st[25] = acc;                                          // == 4096
  }
  __syncthreads();
  if (tid < 25) cur[tid] = st[tid];
  if (tid < 26) starts[b * 32 + tid] = st[tid];
  __syncthreads();
  for (int i = tid; i < BN; i += 256) {
    float x = locs[(b * BN + i) * 2], y = locs[(b * BN + i) * 2 + 1];
    int pos = atomicAdd(&cur[cell_of(x, y)], 1);
    perm[b * BN + pos] = i;
    pack[b * BN + pos] = make_float4(x, y, 0.f, mask[b * BN + i] ? 1.f : 0.f);
  }
}

// -------------------------------------------- feats pre-pack (1024 blk) -----
// fB[b][blk][ch][sl] u32 = (bf16hi<<16|bf16lo) of feats[b][perm_s[blk*16+sl]][ch].
// UNSWIZZLED now (k_out reads it straight to registers; no LDS banks involved).
__global__ __launch_bounds__(256) void k_pack(
    const float* __restrict__ feats, const int* __restrict__ perm_s,
    unsigned* __restrict__ fB) {
  const int b   = blockIdx.x >> 8;
  const int blk = blockIdx.x & 255;
  const int tid = threadIdx.x;
  __shared__ int sidx[16];
  if (tid < 16) sidx[tid] = perm_s[b * BN + blk * 16 + tid];
  __syncthreads();
  const int ch = tid;
  unsigned pk[16];
  #pragma unroll
  for (int sl = 0; sl < 16; sl++) {
    float f = feats[((((size_t)(b << 12)) + sidx[sl]) << 8) + ch];
    unsigned fbt = __float_as_uint(f);
    unsigned hb  = fbt & 0xFFFF0000u;
    float lo = f - __uint_as_float(hb);
    pk[sl] = hb | (__float_as_uint(lo) >> 16);
  }
  unsigned* dst = fB + ((((size_t)b << 8) + blk) << 12) + ch * 16;
  #pragma unroll
  for (int q = 0; q < 4; q++)
    ((uint4*)dst)[q] = make_uint4(pk[q*4], pk[q*4+1], pk[q*4+2], pk[q*4+3]);
}

// ------------------------------------------------------ sparse Sinkhorn -----
// r4-verified; see prior rounds for the plain-sum / Z-leak argument.
__global__ __launch_bounds__(256) void k_sink(const float4* __restrict__ opp,
                                              float4* __restrict__ own,
                                              const int* __restrict__ opp_starts,
                                              const int* __restrict__ Zin,
                                              int* __restrict__ Zout,
                                              int zero_invalid) {
  const int wv   = threadIdx.x >> 6;
  const int lane = threadIdx.x & 63;
  const int rowb = blockIdx.x * 16 + wv * 4;
  const int b    = rowb >> 12;
  float4 me[4];
  float  s[4] = {0.f, 0.f, 0.f, 0.f};
  int ryLo = 5, ryHi = -1, rxLo = 5, rxHi = -1;
  #pragma unroll
  for (int i = 0; i < 4; i++) {
    me[i] = own[rowb + i];
    if (me[i].w != 0.f) {
      int cell = cell_of(me[i].x, me[i].y);
      int cy = cell / 5, cx = cell % 5;
      ryLo = min(ryLo, max(cy - 1, 0)); ryHi = max(ryHi, min(cy + 1, 4));
      rxLo = min(rxLo, max(cx - 1, 0)); rxHi = max(rxHi, min(cx + 1, 4));
    }
  }
  for (int ry = ryLo; ry <= ryHi; ry++) {
    const int r0 = opp_starts[b * 32 + ry * 5 + rxLo];
    const int r1 = opp_starts[b * 32 + ry * 5 + rxHi + 1];
    for (int j = r0 + lane; j < r1; j += 64) {
      float4 o = opp[b * BN + j];
      #pragma unroll
      for (int i = 0; i < 4; i++) {
        float dx = me[i].x - o.x, dy = me[i].y - o.y;
        float d2 = fmaf(dx, dx, dy * dy);
        bool  c  = (d2 < T2) && (o.w != 0.f) && (me[i].w != 0.f);
        float t  = c ? fmaf(d2, -INV_EPS, o.z) : -3e30f;
        s[i] += __expf(t);
      }
    }
  }
  #pragma unroll
  for (int i = 0; i < 4; i++)
    for (int off = 32; off > 0; off >>= 1) s[i] += __shfl_xor(s[i], off);
  if (lane == 0) {
    const float Zf = (float)Zin[b];
    #pragma unroll
    for (int i = 0; i < 4; i++) {
      float ss  = s[i] + Zf;
      float val = (ss > 0.f) ? -logf(ss) : 1.0e9f;
      if (zero_invalid && me[i].w == 0.f) val = 0.f;
      own[rowb + i] = make_float4(me[i].x, me[i].y, val, me[i].w);
      if (val == 1.0e9f) atomicAdd(&Zout[b], 1);
    }
  }
}

// ------------------------------------------------- sparse attn @ feats ------
// MFMA v6: REGISTER-DIRECT, occupancy-first. Diagnosis (r8-r11): four sync
// structures all ~222us with ~2 waves/SIMD and ~70% no-issue => latency-bound
// at low occupancy. Fix: delete LDS staging entirely (fB is pre-packed, so
// each lane loads its A-fragment straight from global: 2x16B contiguous per
// mt, coalesced), s-rows straight from L2-resident s_sorted. LDS = tL + Dl
// bounce only (~35KB -> 4 blocks/CU); __launch_bounds__(256,4) caps VGPR at
// 128 -> 16 waves/CU (4/SIMD), 2x the latency hiding. A-frags prefetched one
// round ahead (register rotation, r6-proven); compiler inserts waitcnts.
#define NITEMS (BB * 25 * 3 * 12)   // b x cell x rsel x 32-tgt chunk = 3600

__global__ __launch_bounds__(256, 4) void k_out(
    const unsigned* __restrict__ fB, const float4* __restrict__ t_sorted,
    const float4* __restrict__ s_sorted, const int* __restrict__ perm_t,
    const int* __restrict__ starts_t, const int* __restrict__ starts_s,
    int* __restrict__ qcnt, float* __restrict__ out) {
  __shared__ float4 tL[32];
  __shared__ __align__(16) float Dl[32 * 268];   // 34.3 KB bounce
  __shared__ int qi;

  const int tid  = threadIdx.x;
  const int lane = tid & 63;
  const int w    = tid >> 6;
  const int kg   = lane >> 5;                // k-half: src kg*8 .. +7
  const int ln   = lane & 31;                // n(tm) for B/D, m(ch) for A

  for (;;) {
    if (tid == 0) qi = atomicAdd(qcnt, 1);
    __syncthreads();
    const int item = qi;
    __syncthreads();
    if (item >= NITEMS) break;
    const int b    = item / 900;               // 900 = 25*3*12
    const int r1_  = item % 900;
    const int cell = r1_ / 36;
    const int r2_  = r1_ % 36;
    const int rsel = r2_ / 12, chunk = r2_ % 12;
    const int cy = cell / 5, cx = cell % 5;
    const int ry = cy + rsel - 1;
    if (ry < 0 || ry > 4) continue;
    const int t0 = starts_t[b * 32 + cell], t1 = starts_t[b * 32 + cell + 1];
    const int base = t0 + chunk * 32;
    if (base >= t1) continue;
    const int rx0 = max(cx - 1, 0), rx1 = min(cx + 1, 4);
    const int s0 = starts_s[b * 32 + ry * 5 + rx0];
    const int s1 = starts_s[b * 32 + ry * 5 + rx1 + 1];
    if (s0 >= s1) continue;
    const int nt = min(32, t1 - base);

    if (tid < 32)
      tL[tid] = (tid < nt) ? t_sorted[b * BN + base + tid]
                           : make_float4(0.f, 0.f, 0.f, 0.f);  // tv=0 -> attn 0
    __syncthreads();
    const float4 t4a = tL[ln];
    const int sB = b * BN;
    const int blk0 = s0 >> 4;
    const int nBlk = ((s1 + 15) >> 4) - blk0;

    const unsigned* fBb = fB + (((size_t)b) << 20);
    const int aoff0 = (w * 64 + ln) * 16 + kg * 8;        // mt=0 frag offset
    const int aoff1 = aoff0 + 512;                        // mt=1 (+32 ch)

    // ---- prologue: round-0 A fragments into registers ----------------------
    const unsigned* g0p = fBb + ((size_t)blk0 << 12);
    uint4 cA00 = *(const uint4*)(g0p + aoff0);
    uint4 cA01 = *(const uint4*)(g0p + aoff0 + 4);
    uint4 cA10 = *(const uint4*)(g0p + aoff1);
    uint4 cA11 = *(const uint4*)(g0p + aoff1 + 4);

    f32x16 acc0, acc1;
    #pragma unroll
    for (int i = 0; i < 16; i++) { acc0[i] = 0.f; acc1[i] = 0.f; }

    for (int r = 0; r < nBlk; r++) {
      // ---- prefetch next round's A fragments (register rotation) -----------
      const int tn = blk0 + min(r + 1, nBlk - 1);
      const unsigned* gn = fBb + ((size_t)tn << 12);
      uint4 nA00 = *(const uint4*)(gn + aoff0);
      uint4 nA01 = *(const uint4*)(gn + aoff0 + 4);
      uint4 nA10 = *(const uint4*)(gn + aoff1);
      uint4 nA11 = *(const uint4*)(gn + aoff1 + 4);
      // ---- current round S rows (L2-hot broadcast loads) -------------------
      const int j0 = (blk0 + r) * 16 + kg * 8;
      float4 s4v[8];
      #pragma unroll
      for (int e = 0; e < 8; e++)
        s4v[e] = s_sorted[sB + j0 + e];
      // ---- B fragments (attn) straight into registers ----------------------
      union { unsigned u[4]; bf16x8 v; } BH, BL;
      #pragma unroll
      for (int i = 0; i < 4; i++) {
        unsigned hh[2], ll[2];
        #pragma unroll
        for (int p = 0; p < 2; p++) {
          const int e = 2 * i + p;
          float4 s4 = s4v[e];
          int j = j0 + e;
          float dx = t4a.x - s4.x, dy = t4a.y - s4.y;
          float d2 = fmaf(dx, dx, dy * dy);
          bool  c  = (j >= s0) && (j < s1) && (d2 < T2) &&
                     (s4.w != 0.f) && (t4a.w != 0.f);
          float a  = c ? __expf(fmaf(d2, -INV_EPS, t4a.z + s4.z)) : 0.f;
          unsigned ab = __float_as_uint(a);
          unsigned hb = ab & 0xFFFF0000u;
          float alo = a - __uint_as_float(hb);
          hh[p] = ab >> 16;
          ll[p] = __float_as_uint(alo) >> 16;
        }
        BH.u[i] = hh[0] | (hh[1] << 16);
        BL.u[i] = ll[0] | (ll[1] << 16);
      }
      // ---- A unpack + 6 MFMA -----------------------------------------------
      #pragma unroll
      for (int mt = 0; mt < 2; mt++) {
        union { uint4 q[2]; unsigned u[8]; } A;
        A.q[0] = (mt == 0) ? cA00 : cA10;
        A.q[1] = (mt == 0) ? cA01 : cA11;
        union { unsigned u[4]; bf16x8 v; } AH, AL;
        #pragma unroll
        for (int i = 0; i < 4; i++) {
          AH.u[i] = (A.u[2*i] >> 16)     | (A.u[2*i+1] & 0xFFFF0000u);
          AL.u[i] = (A.u[2*i] & 0xFFFFu) | (A.u[2*i+1] << 16);
        }
        if (mt == 0) {
          acc0 = __builtin_amdgcn_mfma_f32_32x32x16_bf16(AH.v, BH.v, acc0, 0, 0, 0);
          acc0 = __builtin_amdgcn_mfma_f32_32x32x16_bf16(AH.v, BL.v, acc0, 0, 0, 0);
          acc0 = __builtin_amdgcn_mfma_f32_32x32x16_bf16(AL.v, BH.v, acc0, 0, 0, 0);
        } else {
          acc1 = __builtin_amdgcn_mfma_f32_32x32x16_bf16(AH.v, BH.v, acc1, 0, 0, 0);
          acc1 = __builtin_amdgcn_mfma_f32_32x32x16_bf16(AH.v, BL.v, acc1, 0, 0, 0);
          acc1 = __builtin_amdgcn_mfma_f32_32x32x16_bf16(AL.v, BH.v, acc1, 0, 0, 0);
        }
      }
      cA00 = nA00; cA01 = nA01; cA10 = nA10; cA11 = nA11;  // rotate
    }

    // ---- epilogue: Dl bounce + coalesced atomic flush ------------------------
    __syncthreads();                           // Dl free (prev flush done)
    #pragma unroll
    for (int mt = 0; mt < 2; mt++) {
      #pragma unroll
      for (int rg = 0; rg < 4; rg++) {         // regs rg*4..+3 -> rows 8rg+4kg..+3
        int chb = w * 64 + mt * 32 + 8 * rg + 4 * kg;
        float4 v;
        if (mt == 0) v = make_float4(acc0[rg*4], acc0[rg*4+1], acc0[rg*4+2], acc0[rg*4+3]);
        else         v = make_float4(acc1[rg*4], acc1[rg*4+1], acc1[rg*4+2], acc1[rg*4+3]);
        *(float4*)&Dl[ln * 268 + chb] = v;
      }
    }
    __syncthreads();
    {
      const int tmg = tid >> 5, chg = tid & 31;
      #pragma unroll
      for (int i = 0; i < 4; i++) {
        int tm = tmg * 4 + i;
        if (tm < nt) {
          int row = perm_t[sB + base + tm];
          float* op = out + (((b << 12) + row) << 8) + chg * 4;
          float4 d0 = *(float4*)&Dl[tm * 268 + chg * 4];
          float4 d1 = *(float4*)&Dl[tm * 268 + 128 + chg * 4];
          atomicAdd(op + 0, d0.x); atomicAdd(op + 1, d0.y);
          atomicAdd(op + 2, d0.z); atomicAdd(op + 3, d0.w);
          atomicAdd(op + 128, d1.x); atomicAdd(op + 129, d1.y);
          atomicAdd(op + 130, d1.z); atomicAdd(op + 131, d1.w);
        }
      }
    }
  }
}

// ----------------------------------------------------------------- launch ---
extern "C" void kernel_launch(void* const* d_in, const int* in_sizes, int n_in,
                              void* d_out, int out_size, void* d_ws, size_t ws_size,
                              hipStream_t stream) {
  const float* feats = (const float*)d_in[0];   // [B,N,C] f32
  const float* slocs = (const float*)d_in[1];   // [B,N,2] f32
  const float* tlocs = (const float*)d_in[2];   // [B,M,2] f32
  const int*   smask = (const int*)d_in[3];     // [B,N] int32 (bool)
  const int*   tmask = (const int*)d_in[4];     // [B,M] int32 (bool)
  float* out = (float*)d_out;

  char* ws = (char*)d_ws;                       // ~660 KB + 16 MB fB
  int*    qcnt     = (int*)(ws);                //   work-queue counter
  int*    Zc       = (int*)(ws + 1024);         //   256 ints; slot 0 stays 0
  int*    starts_t = (int*)(ws + 2048);         //   512 B
  int*    starts_s = (int*)(ws + 2560);         //   512 B
  int*    perm_t   = (int*)(ws + 4096);         //   64 KB
  int*    perm_s   = (int*)(ws + 69632);        //   64 KB
  float4* s_sorted = (float4*)(ws + 135168);    //  256 KB (x,y,v,sv) cell-sorted
  float4* t_sorted = (float4*)(ws + 397312);    //  256 KB (x,y,u,tv) cell-sorted
  unsigned* fB     = (unsigned*)(ws + 663552);  // 16 MB packed feats tiles

  hipMemsetAsync(out, 0, (size_t)out_size * sizeof(float), stream);
  k_bin<<<8, 256, 0, stream>>>(tlocs, slocs, tmask, smask, Zc, qcnt,
                               starts_t, starts_s, perm_t, perm_s,
                               t_sorted, s_sorted);
  k_pack<<<1024, 256, 0, stream>>>(feats, perm_s, fB);
  for (int it = 0; it < 3; it++) {
    k_sink<<<1024, 256, 0, stream>>>(s_sorted, t_sorted, starts_s,
                                     Zc + (it == 0 ? 0 : (2 * it) * 4),
                                     Zc + (2 * it + 1) * 4, 0);
    k_sink<<<1024, 256, 0, stream>>>(t_sorted, s_sorted, starts_t,
                                     Zc + (2 * it + 1) * 4,
                                     Zc + (2 * it + 2) * 4, 1);
  }
  k_out<<<1024, 256, 0, stream>>>(fB, t_sorted, s_sorted, perm_t,
                                  starts_t, starts_s, qcnt, out);
}

// Round 13
// 535.108 us; speedup vs baseline: 1.0446x; 1.0446x over previous
//
#include <hip/hip_runtime.h>
#include <math.h>

// Problem constants (reference: B,N,M,C = 4,4096,4096,256)
#define BB 4
#define BN 4096          // N == M == 4096
#define CC 256
constexpr float T2      = 0.04f;                     // DIST_THRESH^2
constexpr float INV_EPS = (float)(1.0 / 0.01000001); // 1/(EPSILON + 1e-8)

typedef __attribute__((ext_vector_type(8)))  short bf16x8;
typedef __attribute__((ext_vector_type(16))) float f32x16;

__device__ __forceinline__ int cell_of(float x, float y) {
  int cx = (int)(x * 5.0f); cx = cx < 0 ? 0 : (cx > 4 ? 4 : cx);
  int cy = (int)(y * 5.0f); cy = cy < 0 ? 0 : (cy > 4 ? 4 : cy);
  return cy * 5 + cx;
}

// ------------------------------------------------- fused binning (8 blk) ----
__global__ __launch_bounds__(256) void k_bin(
    const float* __restrict__ tlocs, const float* __restrict__ slocs,
    const int* __restrict__ tmask, const int* __restrict__ smask,
    int* __restrict__ Zc, int* __restrict__ qcnt,
    int* __restrict__ starts_t, int* __restrict__ starts_s,
    int* __restrict__ perm_t, int* __restrict__ perm_s,
    float4* __restrict__ t_sorted, float4* __restrict__ s_sorted) {
  const int which = blockIdx.x & 1, b = blockIdx.x >> 1;   // grid = 2*B
  const float* locs = which ? slocs : tlocs;
  const int*   mask = which ? smask : tmask;
  int* starts       = which ? starts_s : starts_t;
  int* perm         = which ? perm_s : perm_t;
  float4* pack      = which ? s_sorted : t_sorted;
  const int tid = threadIdx.x;
  if (blockIdx.x == 0) {
    Zc[tid] = 0;                                           // 256 ints = 1 KB
    if (tid == 0) qcnt[0] = 0;                             // k_out work queue
  }
  __shared__ int cnt[25];
  __shared__ int st[26];
  __shared__ int cur[25];
  if (tid < 25) cnt[tid] = 0;
  __syncthreads();
  for (int i = tid; i < BN; i += 256)
    atomicAdd(&cnt[cell_of(locs[(b * BN + i) * 2], locs[(b * BN + i) * 2 + 1])], 1);
  __syncthreads();
  if (tid == 0) {
    int acc = 0;
    for (int c = 0; c < 25; c++) { st[c] = acc; acc += cnt[c]; }
    st[25] = acc;                                          // == 4096
  }
  __syncthreads();
  if (tid < 25) cur[tid] = st[tid];
  if (tid < 26) starts[b * 32 + tid] = st[tid];
  __syncthreads();
  for (int i = tid; i < BN; i += 256) {
    float x = locs[(b * BN + i) * 2], y = locs[(b * BN + i) * 2 + 1];
    int pos = atomicAdd(&cur[cell_of(x, y)], 1);
    perm[b * BN + pos] = i;
    pack[b * BN + pos] = make_float4(x, y, 0.f, mask[b * BN + i] ? 1.f : 0.f);
  }
}

// -------------------------------------------- feats pre-pack (1024 blk) -----
// fB[b][blk][ch][sl] u32 = (bf16hi<<16|bf16lo) of feats[b][perm_s[blk*16+sl]][ch].
__global__ __launch_bounds__(256) void k_pack(
    const float* __restrict__ feats, const int* __restrict__ perm_s,
    unsigned* __restrict__ fB) {
  const int b   = blockIdx.x >> 8;
  const int blk = blockIdx.x & 255;
  const int tid = threadIdx.x;
  __shared__ int sidx[16];
  if (tid < 16) sidx[tid] = perm_s[b * BN + blk * 16 + tid];
  __syncthreads();
  const int ch = tid;
  unsigned pk[16];
  #pragma unroll
  for (int sl = 0; sl < 16; sl++) {
    float f = feats[((((size_t)(b << 12)) + sidx[sl]) << 8) + ch];
    unsigned fbt = __float_as_uint(f);
    unsigned hb  = fbt & 0xFFFF0000u;
    float lo = f - __uint_as_float(hb);
    pk[sl] = hb | (__float_as_uint(lo) >> 16);
  }
  unsigned* dst = fB + ((((size_t)b << 8) + blk) << 12) + ch * 16;
  #pragma unroll
  for (int q = 0; q < 4; q++)
    ((uint4*)dst)[q] = make_uint4(pk[q*4], pk[q*4+1], pk[q*4+2], pk[q*4+3]);
}

// ------------------------------------------------------ sparse Sinkhorn -----
// r4-verified; see prior rounds for the plain-sum / Z-leak argument.
__global__ __launch_bounds__(256) void k_sink(const float4* __restrict__ opp,
                                              float4* __restrict__ own,
                                              const int* __restrict__ opp_starts,
                                              const int* __restrict__ Zin,
                                              int* __restrict__ Zout,
                                              int zero_invalid) {
  const int wv   = threadIdx.x >> 6;
  const int lane = threadIdx.x & 63;
  const int rowb = blockIdx.x * 16 + wv * 4;
  const int b    = rowb >> 12;
  float4 me[4];
  float  s[4] = {0.f, 0.f, 0.f, 0.f};
  int ryLo = 5, ryHi = -1, rxLo = 5, rxHi = -1;
  #pragma unroll
  for (int i = 0; i < 4; i++) {
    me[i] = own[rowb + i];
    if (me[i].w != 0.f) {
      int cell = cell_of(me[i].x, me[i].y);
      int cy = cell / 5, cx = cell % 5;
      ryLo = min(ryLo, max(cy - 1, 0)); ryHi = max(ryHi, min(cy + 1, 4));
      rxLo = min(rxLo, max(cx - 1, 0)); rxHi = max(rxHi, min(cx + 1, 4));
    }
  }
  for (int ry = ryLo; ry <= ryHi; ry++) {
    const int r0 = opp_starts[b * 32 + ry * 5 + rxLo];
    const int r1 = opp_starts[b * 32 + ry * 5 + rxHi + 1];
    for (int j = r0 + lane; j < r1; j += 64) {
      float4 o = opp[b * BN + j];
      #pragma unroll
      for (int i = 0; i < 4; i++) {
        float dx = me[i].x - o.x, dy = me[i].y - o.y;
        float d2 = fmaf(dx, dx, dy * dy);
        bool  c  = (d2 < T2) && (o.w != 0.f) && (me[i].w != 0.f);
        float t  = c ? fmaf(d2, -INV_EPS, o.z) : -3e30f;
        s[i] += __expf(t);
      }
    }
  }
  #pragma unroll
  for (int i = 0; i < 4; i++)
    for (int off = 32; off > 0; off >>= 1) s[i] += __shfl_xor(s[i], off);
  if (lane == 0) {
    const float Zf = (float)Zin[b];
    #pragma unroll
    for (int i = 0; i < 4; i++) {
      float ss  = s[i] + Zf;
      float val = (ss > 0.f) ? -logf(ss) : 1.0e9f;
      if (zero_invalid && me[i].w == 0.f) val = 0.f;
      own[rowb + i] = make_float4(me[i].x, me[i].y, val, me[i].w);
      if (val == 1.0e9f) atomicAdd(&Zout[b], 1);
    }
  }
}

// ------------------------------------------------- sparse attn @ feats ------
// MFMA v7: FULL-BOX items -> ZERO-ATOMIC epilogue. Evidence (r0-r12): the
// atomicAdd flush is ~80-90us of k_out (r7 A/B: 2x atomics = +81us; WRITE
// constant 170MB across five otherwise-different structures pinned at
// 220-232us). One item now = (b, cell, 32-tgt chunk) over ALL box rows (up
// to 3 contiguous source segments), so each output row's complete sum is
// produced by exactly ONE block -> plain coalesced global_store_dwordx4.
// Every target is in exactly one item; all rows stored exactly once.
// Inner round body unchanged from r12 (register-direct A-frags from packed
// fB, one-round register rotation, in-register B build, 6x 3-term hi/lo
// mfma_f32_32x32x16_bf16); persistent queue, __launch_bounds__(256,4).
#define NITEMS (BB * 25 * 12)   // b x cell x 32-tgt chunk = 1200

__global__ __launch_bounds__(256, 4) void k_out(
    const unsigned* __restrict__ fB, const float4* __restrict__ t_sorted,
    const float4* __restrict__ s_sorted, const int* __restrict__ perm_t,
    const int* __restrict__ starts_t, const int* __restrict__ starts_s,
    int* __restrict__ qcnt, float* __restrict__ out) {
  __shared__ float4 tL[32];
  __shared__ __align__(16) float Dl[32 * 268];   // 34.3 KB bounce
  __shared__ int qi;

  const int tid  = threadIdx.x;
  const int lane = tid & 63;
  const int w    = tid >> 6;
  const int kg   = lane >> 5;                // k-half: src kg*8 .. +7
  const int ln   = lane & 31;                // n(tm) for B/D, m(ch) for A

  for (;;) {
    if (tid == 0) qi = atomicAdd(qcnt, 1);
    __syncthreads();
    const int item = qi;
    __syncthreads();
    if (item >= NITEMS) break;
    const int b    = item / 300;               // 300 = 25*12
    const int r1_  = item % 300;
    const int cell = r1_ / 12;
    const int chunk = r1_ % 12;
    const int cy = cell / 5, cx = cell % 5;
    const int t0 = starts_t[b * 32 + cell], t1 = starts_t[b * 32 + cell + 1];
    const int base = t0 + chunk * 32;
    if (base >= t1) continue;                  // chunk doesn't exist
    const int ry0 = max(cy - 1, 0), ry1 = min(cy + 1, 4);
    const int rx0 = max(cx - 1, 0), rx1 = min(cx + 1, 4);
    const int nt = min(32, t1 - base);

    if (tid < 32)
      tL[tid] = (tid < nt) ? t_sorted[b * BN + base + tid]
                           : make_float4(0.f, 0.f, 0.f, 0.f);  // tv=0 -> attn 0
    __syncthreads();
    const float4 t4a = tL[ln];
    const int sB = b * BN;
    const unsigned* fBb = fB + (((size_t)b) << 20);
    const int aoff0 = (w * 64 + ln) * 16 + kg * 8;        // mt=0 frag offset
    const int aoff1 = aoff0 + 512;                        // mt=1 (+32 ch)

    f32x16 acc0, acc1;
    #pragma unroll
    for (int i = 0; i < 16; i++) { acc0[i] = 0.f; acc1[i] = 0.f; }

    // ---- iterate the (up to 3) contiguous source segments of the box ------
    for (int ry = ry0; ry <= ry1; ry++) {
      const int s0 = starts_s[b * 32 + ry * 5 + rx0];
      const int s1 = starts_s[b * 32 + ry * 5 + rx1 + 1];
      if (s0 >= s1) continue;
      const int blk0 = s0 >> 4;
      const int nBlk = ((s1 + 15) >> 4) - blk0;

      const unsigned* g0p = fBb + ((size_t)blk0 << 12);
      uint4 cA00 = *(const uint4*)(g0p + aoff0);
      uint4 cA01 = *(const uint4*)(g0p + aoff0 + 4);
      uint4 cA10 = *(const uint4*)(g0p + aoff1);
      uint4 cA11 = *(const uint4*)(g0p + aoff1 + 4);

      for (int r = 0; r < nBlk; r++) {
        // prefetch next round's A fragments (register rotation)
        const int tn = blk0 + min(r + 1, nBlk - 1);
        const unsigned* gn = fBb + ((size_t)tn << 12);
        uint4 nA00 = *(const uint4*)(gn + aoff0);
        uint4 nA01 = *(const uint4*)(gn + aoff0 + 4);
        uint4 nA10 = *(const uint4*)(gn + aoff1);
        uint4 nA11 = *(const uint4*)(gn + aoff1 + 4);
        // current round S rows (L2-hot broadcast loads)
        const int j0 = (blk0 + r) * 16 + kg * 8;
        float4 s4v[8];
        #pragma unroll
        for (int e = 0; e < 8; e++)
          s4v[e] = s_sorted[sB + j0 + e];
        // B fragments (attn) straight into registers
        union { unsigned u[4]; bf16x8 v; } BH, BL;
        #pragma unroll
        for (int i = 0; i < 4; i++) {
          unsigned hh[2], ll[2];
          #pragma unroll
          for (int p = 0; p < 2; p++) {
            const int e = 2 * i + p;
            float4 s4 = s4v[e];
            int j = j0 + e;
            float dx = t4a.x - s4.x, dy = t4a.y - s4.y;
            float d2 = fmaf(dx, dx, dy * dy);
            bool  c  = (j >= s0) && (j < s1) && (d2 < T2) &&
                       (s4.w != 0.f) && (t4a.w != 0.f);
            float a  = c ? __expf(fmaf(d2, -INV_EPS, t4a.z + s4.z)) : 0.f;
            unsigned ab = __float_as_uint(a);
            unsigned hb = ab & 0xFFFF0000u;
            float alo = a - __uint_as_float(hb);
            hh[p] = ab >> 16;
            ll[p] = __float_as_uint(alo) >> 16;
          }
          BH.u[i] = hh[0] | (hh[1] << 16);
          BL.u[i] = ll[0] | (ll[1] << 16);
        }
        // A unpack + 6 MFMA
        #pragma unroll
        for (int mt = 0; mt < 2; mt++) {
          union { uint4 q[2]; unsigned u[8]; } A;
          A.q[0] = (mt == 0) ? cA00 : cA10;
          A.q[1] = (mt == 0) ? cA01 : cA11;
          union { unsigned u[4]; bf16x8 v; } AH, AL;
          #pragma unroll
          for (int i = 0; i < 4; i++) {
            AH.u[i] = (A.u[2*i] >> 16)     | (A.u[2*i+1] & 0xFFFF0000u);
            AL.u[i] = (A.u[2*i] & 0xFFFFu) | (A.u[2*i+1] << 16);
          }
          if (mt == 0) {
            acc0 = __builtin_amdgcn_mfma_f32_32x32x16_bf16(AH.v, BH.v, acc0, 0, 0, 0);
            acc0 = __builtin_amdgcn_mfma_f32_32x32x16_bf16(AH.v, BL.v, acc0, 0, 0, 0);
            acc0 = __builtin_amdgcn_mfma_f32_32x32x16_bf16(AL.v, BH.v, acc0, 0, 0, 0);
          } else {
            acc1 = __builtin_amdgcn_mfma_f32_32x32x16_bf16(AH.v, BH.v, acc1, 0, 0, 0);
            acc1 = __builtin_amdgcn_mfma_f32_32x32x16_bf16(AH.v, BL.v, acc1, 0, 0, 0);
            acc1 = __builtin_amdgcn_mfma_f32_32x32x16_bf16(AL.v, BH.v, acc1, 0, 0, 0);
          }
        }
        cA00 = nA00; cA01 = nA01; cA10 = nA10; cA11 = nA11;  // rotate
      }
    }

    // ---- epilogue: Dl bounce + PLAIN coalesced stores (row written once) ---
    __syncthreads();                           // Dl free (prev flush done)
    #pragma unroll
    for (int mt = 0; mt < 2; mt++) {
      #pragma unroll
      for (int rg = 0; rg < 4; rg++) {         // regs rg*4..+3 -> rows 8rg+4kg..+3
        int chb = w * 64 + mt * 32 + 8 * rg + 4 * kg;
        float4 v;
        if (mt == 0) v = make_float4(acc0[rg*4], acc0[rg*4+1], acc0[rg*4+2], acc0[rg*4+3]);
        else         v = make_float4(acc1[rg*4], acc1[rg*4+1], acc1[rg*4+2], acc1[rg*4+3]);
        *(float4*)&Dl[ln * 268 + chb] = v;
      }
    }
    __syncthreads();
    {
      const int tmg = tid >> 5, chg = tid & 31;
      #pragma unroll
      for (int i = 0; i < 4; i++) {
        int tm = tmg * 4 + i;
        if (tm < nt) {
          int row = perm_t[sB + base + tm];
          float* op = out + (((b << 12) + row) << 8) + chg * 4;
          *(float4*)(op)       = *(float4*)&Dl[tm * 268 + chg * 4];
          *(float4*)(op + 128) = *(float4*)&Dl[tm * 268 + 128 + chg * 4];
        }
      }
    }
  }
}

// ----------------------------------------------------------------- launch ---
extern "C" void kernel_launch(void* const* d_in, const int* in_sizes, int n_in,
                              void* d_out, int out_size, void* d_ws, size_t ws_size,
                              hipStream_t stream) {
  const float* feats = (const float*)d_in[0];   // [B,N,C] f32
  const float* slocs = (const float*)d_in[1];   // [B,N,2] f32
  const float* tlocs = (const float*)d_in[2];   // [B,M,2] f32
  const int*   smask = (const int*)d_in[3];     // [B,N] int32 (bool)
  const int*   tmask = (const int*)d_in[4];     // [B,M] int32 (bool)
  float* out = (float*)d_out;

  char* ws = (char*)d_ws;                       // ~660 KB + 16 MB fB
  int*    qcnt     = (int*)(ws);                //   work-queue counter
  int*    Zc       = (int*)(ws + 1024);         //   256 ints; slot 0 stays 0
  int*    starts_t = (int*)(ws + 2048);         //   512 B
  int*    starts_s = (int*)(ws + 2560);         //   512 B
  int*    perm_t   = (int*)(ws + 4096);         //   64 KB
  int*    perm_s   = (int*)(ws + 69632);        //   64 KB
  float4* s_sorted = (float4*)(ws + 135168);    //  256 KB (x,y,v,sv) cell-sorted
  float4* t_sorted = (float4*)(ws + 397312);    //  256 KB (x,y,u,tv) cell-sorted
  unsigned* fB     = (unsigned*)(ws + 663552);  // 16 MB packed feats tiles

  hipMemsetAsync(out, 0, (size_t)out_size * sizeof(float), stream);
  k_bin<<<8, 256, 0, stream>>>(tlocs, slocs, tmask, smask, Zc, qcnt,
                               starts_t, starts_s, perm_t, perm_s,
                               t_sorted, s_sorted);
  k_pack<<<1024, 256, 0, stream>>>(feats, perm_s, fB);
  for (int it = 0; it < 3; it++) {
    k_sink<<<1024, 256, 0, stream>>>(s_sorted, t_sorted, starts_s,
                                     Zc + (it == 0 ? 0 : (2 * it) * 4),
                                     Zc + (2 * it + 1) * 4, 0);
    k_sink<<<1024, 256, 0, stream>>>(t_sorted, s_sorted, starts_t,
                                     Zc + (2 * it + 1) * 4,
                                     Zc + (2 * it + 2) * 4, 1);
  }
  k_out<<<1024, 256, 0, stream>>>(fB, t_sorted, s_sorted, perm_t,
                                  starts_t, starts_s, qcnt, out);
}